// Round 7
// baseline (104.557 us; speedup 1.0000x reference)
//
#include <hip/hip_runtime.h>
#include <math.h>

#define NN 100000
#define NE 500000

// ---------------------------------------------------------------------------
// Kernel 1: per-node projection.
//   AB[n][0:64]   = h[n] @ W1[0:128, :]   + b1      (source-role, b1 folded)
//   AB[n][64:128] = h[n] @ W1[128:256, :]           (target-role)
//
// R7 = R6's dual-pipe structure (h via LDS, W via VMEM double-buffer,
// barrier-free main loop) at HALF the tile: 64 nodes/block.
//   * LDS 33.8 KB -> 4 blocks/CU (R6's 68 KB capped at 2; occupancy never
//     exceeded ~15% and VALUBusy pinned at ~38% across R1/R3/R6).
//   * acc[4][8] = 32 VGPR -> total ~90 VGPR, no spill, 4+ waves/SIMD.
//   * grid 1563 -> 6.1 blocks/CU demand, smooth packing.
// Per-CU pipe budget at 16 waves: LDS 768 cyc per ~1120-cyc VALU window.
// ---------------------------------------------------------------------------
__global__ __launch_bounds__(256)
void node_proj(const float* __restrict__ h, const float* __restrict__ W1,
               const float* __restrict__ b1, float* __restrict__ AB, int nnodes)
{
    __shared__ float lh[64 * 132];   // 33.8 KB: 64 nodes x 128 k, stride 132
                                     // (132%32==4 -> tnf groups hit banks 0/4/8/12, conflict-free)

    const int t   = threadIdx.x;
    const int tj  = t & 15;      // j-quad: A outputs tj*4..+3, B outputs 64+tj*4..+3
    const int tnf = t >> 4;      // node rows tnf + 16*r, r=0..3
    const int n0  = blockIdx.x * 64;

    // ---- stage h tile once: 64 nodes x 128 k, fully coalesced ----
#pragma unroll
    for (int i = 0; i < 8; ++i) {
        int flat = i * 256 + t;       // 0..2047
        int nl = flat >> 5;           // 0..63
        int c  = flat & 31;           // float4 chunk
        int ng = n0 + nl;
        float4 v = make_float4(0.f, 0.f, 0.f, 0.f);
        if (ng < nnodes) v = *(const float4*)&h[(size_t)ng * 128 + c * 4];
        *(float4*)&lh[nl * 132 + c * 4] = v;
    }
    __syncthreads();

    const float* wa_base = W1 + tj * 4;              // A: W1[k][tj*4..]
    const float* wb_base = W1 + 128 * 64 + tj * 4;   // B: W1[128+k][tj*4..]

    float acc[4][8];
    {
        float4 bv = *(const float4*)&b1[tj * 4];
#pragma unroll
        for (int r = 0; r < 4; ++r) {
            acc[r][0] = bv.x; acc[r][1] = bv.y; acc[r][2] = bv.z; acc[r][3] = bv.w;
            acc[r][4] = 0.f;  acc[r][5] = 0.f;  acc[r][6] = 0.f;  acc[r][7] = 0.f;
        }
    }

    // W double buffers (named -> static indexing, no scratch)
    float4 A0[4], B0[4], A1[4], B1[4];
#pragma unroll
    for (int kk = 0; kk < 4; ++kk) {
        A0[kk] = *(const float4*)&wa_base[kk * 64];
        B0[kk] = *(const float4*)&wb_base[kk * 64];
    }

#define LOAD_W(AX, BX, K4)                                              \
    _Pragma("unroll")                                                   \
    for (int kk = 0; kk < 4; ++kk) {                                    \
        AX[kk] = *(const float4*)&wa_base[((K4) * 4 + kk) * 64];        \
        BX[kk] = *(const float4*)&wb_base[((K4) * 4 + kk) * 64];        \
    }

#define COMPUTE(AX, BX, K4)                                             \
    {                                                                   \
        float4 hv[4];                                                   \
        _Pragma("unroll")                                               \
        for (int r = 0; r < 4; ++r)                                     \
            hv[r] = *(const float4*)&lh[(tnf + 16 * r) * 132 + (K4) * 4]; \
        _Pragma("unroll")                                               \
        for (int kk = 0; kk < 4; ++kk) {                                \
            float4 wa = AX[kk], wb = BX[kk];                            \
            _Pragma("unroll")                                           \
            for (int r = 0; r < 4; ++r) {                               \
                float hk = (kk == 0) ? hv[r].x : (kk == 1) ? hv[r].y    \
                         : (kk == 2) ? hv[r].z : hv[r].w;               \
                acc[r][0] += hk * wa.x;                                 \
                acc[r][1] += hk * wa.y;                                 \
                acc[r][2] += hk * wa.z;                                 \
                acc[r][3] += hk * wa.w;                                 \
                acc[r][4] += hk * wb.x;                                 \
                acc[r][5] += hk * wb.y;                                 \
                acc[r][6] += hk * wb.z;                                 \
                acc[r][7] += hk * wb.w;                                 \
            }                                                           \
        }                                                               \
    }

#pragma unroll 1
    for (int k4 = 0; k4 < 30; k4 += 2) {
        LOAD_W(A1, B1, k4 + 1)        // prefetch next while computing current
        COMPUTE(A0, B0, k4)
        LOAD_W(A0, B0, k4 + 2)
        COMPUTE(A1, B1, k4 + 1)
    }
    LOAD_W(A1, B1, 31)
    COMPUTE(A0, B0, 30)
    COMPUTE(A1, B1, 31)

#undef LOAD_W
#undef COMPUTE

    // ---- store: A-half at [0:64], B-half at [64:128] ----
#pragma unroll
    for (int r = 0; r < 4; ++r) {
        int ng = n0 + tnf + 16 * r;
        if (ng >= nnodes) continue;
        float* orow = AB + (size_t)ng * 128;
        *(float4*)&orow[tj * 4]      = make_float4(acc[r][0], acc[r][1], acc[r][2], acc[r][3]);
        *(float4*)&orow[64 + tj * 4] = make_float4(acc[r][4], acc[r][5], acc[r][6], acc[r][7]);
    }
}

// ---------------------------------------------------------------------------
// Kernel 2: per-edge sample. 16 lanes per edge; lane l owns hid[4l..4l+3].
// hid = relu(AB[row][0:64] + AB[col][64:128])   (b1 already folded into A)
// logits = hid @ W2 + b2 ;  weight = (logits + g1 > g0) ? 1 : 0
// ---------------------------------------------------------------------------
__global__ __launch_bounds__(256)
void edge_sample(const float* __restrict__ AB, const float* __restrict__ W2,
                 const float* __restrict__ b2, const float* __restrict__ u,
                 const int* __restrict__ ei, float* __restrict__ out)
{
    int t = threadIdx.x;
    int l = t & 15;
    int e = blockIdx.x * 16 + (t >> 4);

    int row = ei[e];
    int col = ei[NE + e];

    float4 a = *(const float4*)&AB[(size_t)row * 128 + l * 4];
    float4 b = *(const float4*)&AB[(size_t)col * 128 + 64 + l * 4];
    float4 w = *(const float4*)&W2[l * 4];

    float h0 = fmaxf(a.x + b.x, 0.f);
    float h1 = fmaxf(a.y + b.y, 0.f);
    float h2 = fmaxf(a.z + b.z, 0.f);
    float h3 = fmaxf(a.w + b.w, 0.f);

    float p = h0 * w.x + h1 * w.y + h2 * w.z + h3 * w.w;
    p += __shfl_xor(p, 1);
    p += __shfl_xor(p, 2);
    p += __shfl_xor(p, 4);
    p += __shfl_xor(p, 8);

    if (l == 0) {
        float logit = p + b2[0];
        float u0 = u[2 * e];
        float u1 = u[2 * e + 1];
        float g0 = -logf(-logf(u0));
        float g1 = -logf(-logf(u1));
        out[e]      = (logit + g1 > g0) ? 1.0f : 0.0f;  // argmax tie -> 0
        out[NE + e] = logit;
    }
}

// ---------------------------------------------------------------------------
// Fallback (only if ws_size too small): direct per-edge compute, correct but slow.
// ---------------------------------------------------------------------------
__global__ __launch_bounds__(256)
void edge_direct(const float* __restrict__ h, const float* __restrict__ W1,
                 const float* __restrict__ b1, const float* __restrict__ W2,
                 const float* __restrict__ b2, const float* __restrict__ u,
                 const int* __restrict__ ei, float* __restrict__ out)
{
    int t = threadIdx.x;
    int l = t & 15;
    int e = blockIdx.x * 16 + (t >> 4);

    int row = ei[e];
    int col = ei[NE + e];

    float a0 = 0.f, a1 = 0.f, a2 = 0.f, a3 = 0.f;
    const float* hr = h + (size_t)row * 128;
    const float* hc = h + (size_t)col * 128;

    for (int k4 = 0; k4 < 32; ++k4) {
        float4 hv = *(const float4*)&hr[k4 * 4];
#pragma unroll
        for (int kk = 0; kk < 4; ++kk) {
            float4 wr = *(const float4*)&W1[(k4 * 4 + kk) * 64 + l * 4];
            float hval = (&hv.x)[kk];
            a0 += hval * wr.x; a1 += hval * wr.y; a2 += hval * wr.z; a3 += hval * wr.w;
        }
    }
    for (int k4 = 0; k4 < 32; ++k4) {
        float4 hv = *(const float4*)&hc[k4 * 4];
#pragma unroll
        for (int kk = 0; kk < 4; ++kk) {
            float4 wr = *(const float4*)&W1[(128 + k4 * 4 + kk) * 64 + l * 4];
            float hval = (&hv.x)[kk];
            a0 += hval * wr.x; a1 += hval * wr.y; a2 += hval * wr.z; a3 += hval * wr.w;
        }
    }
    float4 bb = *(const float4*)&b1[l * 4];
    float4 w  = *(const float4*)&W2[l * 4];
    float h0 = fmaxf(a0 + bb.x, 0.f);
    float h1 = fmaxf(a1 + bb.y, 0.f);
    float h2 = fmaxf(a2 + bb.z, 0.f);
    float h3 = fmaxf(a3 + bb.w, 0.f);

    float p = h0 * w.x + h1 * w.y + h2 * w.z + h3 * w.w;
    p += __shfl_xor(p, 1);
    p += __shfl_xor(p, 2);
    p += __shfl_xor(p, 4);
    p += __shfl_xor(p, 8);

    if (l == 0) {
        float logit = p + b2[0];
        float u0 = u[2 * e];
        float u1 = u[2 * e + 1];
        float g0 = -logf(-logf(u0));
        float g1 = -logf(-logf(u1));
        out[e]      = (logit + g1 > g0) ? 1.0f : 0.0f;
        out[NE + e] = logit;
    }
}

extern "C" void kernel_launch(void* const* d_in, const int* in_sizes, int n_in,
                              void* d_out, int out_size, void* d_ws, size_t ws_size,
                              hipStream_t stream)
{
    const float* h  = (const float*)d_in[0];
    const float* W1 = (const float*)d_in[1];
    const float* b1 = (const float*)d_in[2];
    const float* W2 = (const float*)d_in[3];
    const float* b2 = (const float*)d_in[4];
    const float* u  = (const float*)d_in[5];
    const int*   ei = (const int*)d_in[6];
    float* out = (float*)d_out;

    const size_t need = (size_t)NN * 128 * sizeof(float);   // 51.2 MB
    if (ws_size >= need) {
        float* AB = (float*)d_ws;
        int nblocks = (NN + 63) / 64;                       // 1563
        node_proj<<<nblocks, 256, 0, stream>>>(h, W1, b1, AB, NN);
        edge_sample<<<NE / 16, 256, 0, stream>>>(AB, W2, b2, u, ei, out);
    } else {
        edge_direct<<<NE / 16, 256, 0, stream>>>(h, W1, b1, W2, b2, u, ei, out);
    }
}